// Round 5
// baseline (9117.274 us; speedup 1.0000x reference)
//
#include <hip/hip_runtime.h>
#include <math.h>

#define D 4096
#define NB 128
#define TSY 128
#define KC 32
#define NTILES (D / TSY)
#define LDP 40   // padded LDS row stride in bf16 elems (80 B)
#define NBLK 256 // fused kernel grid: 1 block/CU, all co-resident

typedef __attribute__((ext_vector_type(8))) short short8;
typedef __attribute__((ext_vector_type(4))) float f32x4;
typedef __attribute__((ext_vector_type(4))) unsigned int uint4v;
typedef unsigned short ush;

__device__ __forceinline__ float softplusf(float x) {
  return fmaxf(x, 0.0f) + log1pf(expf(-fabsf(x)));
}

struct HL { unsigned int h, l; };

// split two fp32 into packed bf16 hi (truncated) and bf16 lo (residual)
__device__ __forceinline__ HL split2(float x0, float x1) {
  unsigned int b0 = __float_as_uint(x0), b1 = __float_as_uint(x1);
  unsigned int h0 = b0 & 0xFFFF0000u, h1 = b1 & 0xFFFF0000u;
  float r0 = x0 - __uint_as_float(h0);
  float r1 = x1 - __uint_as_float(h1);
  HL out;
  out.h = h1 | (h0 >> 16);
  out.l = (__float_as_uint(r1) & 0xFFFF0000u) | (__float_as_uint(r0) >> 16);
  return out;
}

// ---------------- standalone: M = A·A^T + diag(softplus(n)), lower tiles ----------------
__global__ __launch_bounds__(256) void syrk0_kernel(
    const float* __restrict__ Asrc, const float* __restrict__ nvec,
    float* __restrict__ Mout)
{
  __shared__ ush Ah[TSY][LDP], Al[TSY][LDP];
  __shared__ ush Bh[TSY][LDP], Bl[TSY][LDP];

  int b = blockIdx.x;
  int ti = (int)((sqrtf(8.0f * (float)b + 1.0f) - 1.0f) * 0.5f);
  while ((ti + 1) * (ti + 2) / 2 <= b) ++ti;
  while (ti * (ti + 1) / 2 > b) --ti;
  int tj = b - ti * (ti + 1) / 2;
  int row0 = ti * TSY, col0 = tj * TSY;

  int tid = threadIdx.x;
  int lane = tid & 63, wid = tid >> 6;
  int wr = wid >> 1, wc = wid & 1;
  int srow = tid >> 1;
  int scg = (tid & 1) * 16;

  f32x4 acc[4][4];
#pragma unroll
  for (int m = 0; m < 4; ++m)
#pragma unroll
    for (int n = 0; n < 4; ++n) acc[m][n] = (f32x4){0.f, 0.f, 0.f, 0.f};

  int lr16 = lane & 15, kof = (lane >> 4) * 8;

  for (int kk = 0; kk < D; kk += KC) {
    const float* pa = Asrc + (size_t)(row0 + srow) * D + kk + scg;
    const float* pb = Asrc + (size_t)(col0 + srow) * D + kk + scg;
    float4 av0 = *(const float4*)(pa + 0), av1 = *(const float4*)(pa + 4);
    float4 av2 = *(const float4*)(pa + 8), av3 = *(const float4*)(pa + 12);
    float4 bv0 = *(const float4*)(pb + 0), bv1 = *(const float4*)(pb + 4);
    float4 bv2 = *(const float4*)(pb + 8), bv3 = *(const float4*)(pb + 12);

    __syncthreads();
    {
      HL p0 = split2(av0.x, av0.y), p1 = split2(av0.z, av0.w);
      HL p2 = split2(av1.x, av1.y), p3 = split2(av1.z, av1.w);
      HL p4 = split2(av2.x, av2.y), p5 = split2(av2.z, av2.w);
      HL p6 = split2(av3.x, av3.y), p7 = split2(av3.z, av3.w);
      uint4v h0 = {p0.h, p1.h, p2.h, p3.h}, l0 = {p0.l, p1.l, p2.l, p3.l};
      uint4v h1 = {p4.h, p5.h, p6.h, p7.h}, l1 = {p4.l, p5.l, p6.l, p7.l};
      *(uint4v*)&Ah[srow][scg] = h0;  *(uint4v*)&Ah[srow][scg + 8] = h1;
      *(uint4v*)&Al[srow][scg] = l0;  *(uint4v*)&Al[srow][scg + 8] = l1;
    }
    {
      HL p0 = split2(bv0.x, bv0.y), p1 = split2(bv0.z, bv0.w);
      HL p2 = split2(bv1.x, bv1.y), p3 = split2(bv1.z, bv1.w);
      HL p4 = split2(bv2.x, bv2.y), p5 = split2(bv2.z, bv2.w);
      HL p6 = split2(bv3.x, bv3.y), p7 = split2(bv3.z, bv3.w);
      uint4v h0 = {p0.h, p1.h, p2.h, p3.h}, l0 = {p0.l, p1.l, p2.l, p3.l};
      uint4v h1 = {p4.h, p5.h, p6.h, p7.h}, l1 = {p4.l, p5.l, p6.l, p7.l};
      *(uint4v*)&Bh[srow][scg] = h0;  *(uint4v*)&Bh[srow][scg + 8] = h1;
      *(uint4v*)&Bl[srow][scg] = l0;  *(uint4v*)&Bl[srow][scg + 8] = l1;
    }
    __syncthreads();

    short8 ah[4], al[4], bh[4], bl[4];
#pragma unroll
    for (int m = 0; m < 4; ++m) {
      int r = wr * 64 + m * 16 + lr16;
      ah[m] = *(const short8*)&Ah[r][kof];
      al[m] = *(const short8*)&Al[r][kof];
    }
#pragma unroll
    for (int n = 0; n < 4; ++n) {
      int c = wc * 64 + n * 16 + lr16;
      bh[n] = *(const short8*)&Bh[c][kof];
      bl[n] = *(const short8*)&Bl[c][kof];
    }
#pragma unroll
    for (int m = 0; m < 4; ++m)
#pragma unroll
      for (int n = 0; n < 4; ++n) {
        acc[m][n] = __builtin_amdgcn_mfma_f32_16x16x32_bf16(ah[m], bh[n], acc[m][n], 0, 0, 0);
        acc[m][n] = __builtin_amdgcn_mfma_f32_16x16x32_bf16(ah[m], bl[n], acc[m][n], 0, 0, 0);
        acc[m][n] = __builtin_amdgcn_mfma_f32_16x16x32_bf16(al[m], bh[n], acc[m][n], 0, 0, 0);
      }
  }

  int cl = lane & 15, rg = (lane >> 4) * 4;
#pragma unroll
  for (int m = 0; m < 4; ++m) {
#pragma unroll
    for (int n = 0; n < 4; ++n) {
      int gi0 = row0 + wr * 64 + m * 16 + rg;
      int gj = col0 + wc * 64 + n * 16 + cl;
#pragma unroll
      for (int r = 0; r < 4; ++r) {
        int gi = gi0 + r;
        float v = acc[m][n][r];
        if (gi == gj) v += softplusf(nvec[gi]);
        Mout[(size_t)gi * D + gj] = v;
      }
    }
  }
}

// ---------------- fused factorization loop ----------------

__device__ __forceinline__ void grid_barrier(unsigned* bar, unsigned* rel, unsigned* mygen) {
  __syncthreads();
  ++(*mygen);
  if (threadIdx.x == 0) {
    unsigned g = *mygen;
    __threadfence();
    unsigned prev = __hip_atomic_fetch_add(bar, 1u, __ATOMIC_ACQ_REL, __HIP_MEMORY_SCOPE_AGENT);
    if (prev == NBLK - 1) {
      __hip_atomic_store(bar, 0u, __ATOMIC_RELAXED, __HIP_MEMORY_SCOPE_AGENT);
      __hip_atomic_fetch_add(rel, 1u, __ATOMIC_ACQ_REL, __HIP_MEMORY_SCOPE_AGENT);
    } else {
      while (__hip_atomic_load(rel, __ATOMIC_ACQUIRE, __HIP_MEMORY_SCOPE_AGENT) < g) {
        __builtin_amdgcn_s_sleep(2);
      }
    }
    __threadfence();
  }
  __syncthreads();
}

// block 0 only: in-LDS 128x128 Cholesky of diag block at (kb,kb)
__device__ void potrf_device(float* M, int kb, float (*Ls)[NB + 1]) {
  int tid = threadIdx.x;
  float* Msrc = M + (size_t)kb * D + kb;
  for (int idx = tid; idx < NB * NB; idx += 256) {
    int i = idx >> 7, j = idx & (NB - 1);
    Ls[i][j] = (j <= i) ? Msrc[(size_t)i * D + j] : 0.0f;
  }
  __syncthreads();

  int lane = tid & 63, wid = tid >> 6;
  int tx = tid & 15, ty = tid >> 4;

  for (int pp = 0; pp < 8; ++pp) {
    int pc0 = pp * 16;
    if (wid == 0) {
      int ra = lane, rb = lane + 64;
      bool va = (ra >= pc0), vb = (rb >= pc0);
      float xa[16], xb[16];
#pragma unroll
      for (int c = 0; c < 16; ++c) {
        xa[c] = va ? Ls[ra][pc0 + c] : 0.0f;
        xb[c] = vb ? Ls[rb][pc0 + c] : 0.0f;
      }
#pragma unroll
      for (int j = 0; j < 16; ++j) {
        int jj = pc0 + j;
        float dv = (jj < 64) ? __shfl(xa[j], jj) : __shfl(xb[j], jj - 64);
        float s = 1.0f / sqrtf(dv);
        xa[j] *= s;
        xb[j] *= s;
        float mja = (ra > jj) ? xa[j] : 0.0f;
        float mjb = (rb > jj) ? xb[j] : 0.0f;
#pragma unroll
        for (int c = j + 1; c < 16; ++c) {
          int rc = pc0 + c;
          float lc = (rc < 64) ? __shfl(xa[j], rc) : __shfl(xb[j], rc - 64);
          xa[c] -= mja * lc;
          xb[c] -= mjb * lc;
        }
      }
      if (va) {
#pragma unroll
        for (int c = 0; c < 16; ++c) Ls[ra][pc0 + c] = xa[c];
      }
      if (vb) {
#pragma unroll
        for (int c = 0; c < 16; ++c) Ls[rb][pc0 + c] = xb[c];
      }
    }
    __syncthreads();

    int s0 = pc0 + 16;
    if (s0 < NB) {
      int r0 = ty * 8, c0 = tx * 8;
      if (r0 >= s0 && c0 >= s0) {
        float acc[8][8];
#pragma unroll
        for (int rr = 0; rr < 8; ++rr) {
          float4 m0 = *(const float4*)&Ls[r0 + rr][c0];
          float4 m1 = *(const float4*)&Ls[r0 + rr][c0 + 4];
          acc[rr][0] = m0.x; acc[rr][1] = m0.y; acc[rr][2] = m0.z; acc[rr][3] = m0.w;
          acc[rr][4] = m1.x; acc[rr][5] = m1.y; acc[rr][6] = m1.z; acc[rr][7] = m1.w;
        }
#pragma unroll
        for (int q = 0; q < 16; ++q) {
          float av[8], bv[8];
#pragma unroll
          for (int rr = 0; rr < 8; ++rr) av[rr] = Ls[r0 + rr][pc0 + q];
#pragma unroll
          for (int cc = 0; cc < 8; ++cc) bv[cc] = Ls[c0 + cc][pc0 + q];
#pragma unroll
          for (int rr = 0; rr < 8; ++rr)
#pragma unroll
            for (int cc = 0; cc < 8; ++cc) acc[rr][cc] -= av[rr] * bv[cc];
        }
#pragma unroll
        for (int rr = 0; rr < 8; ++rr) {
          *(float4*)&Ls[r0 + rr][c0] =
              make_float4(acc[rr][0], acc[rr][1], acc[rr][2], acc[rr][3]);
          *(float4*)&Ls[r0 + rr][c0 + 4] =
              make_float4(acc[rr][4], acc[rr][5], acc[rr][6], acc[rr][7]);
        }
      }
    }
    __syncthreads();
  }

  for (int idx = tid; idx < NB * NB; idx += 256) {
    int i = idx >> 7, j = idx & (NB - 1);
    if (j <= i) Msrc[(size_t)i * D + j] = Ls[i][j];
  }
}

// all blocks: panel solve rows [kb+NB, D), groups of 8 rows round-robin
__device__ void trsm_device(float* M, int kb, int T, float (*Ls)[NB + 1], float* dinv) {
  int ngroups = T >> 3;
  if ((int)blockIdx.x >= ngroups) return;
  int tid = threadIdx.x;
  const float* Lsrc = M + (size_t)kb * D + kb;
  for (int idx = tid; idx < NB * NB; idx += 256) {
    int i = idx >> 7, j = idx & (NB - 1);
    Ls[i][j] = (j <= i) ? Lsrc[(size_t)i * D + j] : 0.0f;
  }
  __syncthreads();
  if (tid < NB) dinv[tid] = 1.0f / Ls[tid][tid];
  __syncthreads();
  int lane = tid & 63, w = tid >> 6;
  for (int g = blockIdx.x; g < ngroups; g += NBLK) {
    size_t r0 = (size_t)(kb + NB) + (size_t)g * 8 + w * 2;
    float* p0 = M + r0 * D + kb;
    float* p1 = p0 + D;
    float x0l = p0[lane], x0h = p0[64 + lane];
    float x1l = p1[lane], x1h = p1[64 + lane];
    for (int p = 0; p < 64; ++p) {
      float dv = dinv[p];
      float xp0 = __shfl(x0l, p) * dv;
      float xp1 = __shfl(x1l, p) * dv;
      float Llo = Ls[lane][p];
      float Lhi = Ls[64 + lane][p];
      if (lane == p)      { x0l = xp0; x1l = xp1; }
      else if (lane > p)  { x0l -= xp0 * Llo; x1l -= xp1 * Llo; }
      x0h -= xp0 * Lhi;
      x1h -= xp1 * Lhi;
    }
    for (int p = 64; p < NB; ++p) {
      int q = p - 64;
      float dv = dinv[p];
      float xp0 = __shfl(x0h, q) * dv;
      float xp1 = __shfl(x1h, q) * dv;
      float Lhi = Ls[64 + lane][p];
      if (lane == q)      { x0h = xp0; x1h = xp1; }
      else if (lane > q)  { x0h -= xp0 * Lhi; x1h -= xp1 * Lhi; }
    }
    p0[lane] = x0l; p0[64 + lane] = x0h;
    p1[lane] = x1l; p1[64 + lane] = x1h;
  }
}

// all blocks: trailing update tiles round-robin; Mout -= X·X^T
__device__ void syrk1_device(float* M, int kb, int t, unsigned char* smem) {
  ush (*Ah)[LDP] = (ush(*)[LDP])(smem);
  ush (*Al)[LDP] = (ush(*)[LDP])(smem + 10240);
  ush (*Bh)[LDP] = (ush(*)[LDP])(smem + 20480);
  ush (*Bl)[LDP] = (ush(*)[LDP])(smem + 30720);
  const float* Asrc = M + (size_t)(kb + NB) * D + kb;
  float* Mout = M + (size_t)(kb + NB) * D + (kb + NB);
  int ntiles = t * (t + 1) / 2;

  int tid = threadIdx.x;
  int lane = tid & 63, wid = tid >> 6;
  int wr = wid >> 1, wc = wid & 1;
  int srow = tid >> 1;
  int scg = (tid & 1) * 16;
  int lr16 = lane & 15, kof = (lane >> 4) * 8;
  int cl = lane & 15, rg = (lane >> 4) * 4;

  for (int s = blockIdx.x; s < ntiles; s += NBLK) {
    int ti = (int)((sqrtf(8.0f * (float)s + 1.0f) - 1.0f) * 0.5f);
    while ((ti + 1) * (ti + 2) / 2 <= s) ++ti;
    while (ti * (ti + 1) / 2 > s) --ti;
    int tj = s - ti * (ti + 1) / 2;
    int row0 = ti * TSY, col0 = tj * TSY;

    f32x4 acc[4][4];
#pragma unroll
    for (int m = 0; m < 4; ++m)
#pragma unroll
      for (int n = 0; n < 4; ++n) acc[m][n] = (f32x4){0.f, 0.f, 0.f, 0.f};

    for (int kk = 0; kk < NB; kk += KC) {
      const float* pa = Asrc + (size_t)(row0 + srow) * D + kk + scg;
      const float* pb = Asrc + (size_t)(col0 + srow) * D + kk + scg;
      float4 av0 = *(const float4*)(pa + 0), av1 = *(const float4*)(pa + 4);
      float4 av2 = *(const float4*)(pa + 8), av3 = *(const float4*)(pa + 12);
      float4 bv0 = *(const float4*)(pb + 0), bv1 = *(const float4*)(pb + 4);
      float4 bv2 = *(const float4*)(pb + 8), bv3 = *(const float4*)(pb + 12);

      __syncthreads();
      {
        HL p0 = split2(av0.x, av0.y), p1 = split2(av0.z, av0.w);
        HL p2 = split2(av1.x, av1.y), p3 = split2(av1.z, av1.w);
        HL p4 = split2(av2.x, av2.y), p5 = split2(av2.z, av2.w);
        HL p6 = split2(av3.x, av3.y), p7 = split2(av3.z, av3.w);
        uint4v h0 = {p0.h, p1.h, p2.h, p3.h}, l0 = {p0.l, p1.l, p2.l, p3.l};
        uint4v h1 = {p4.h, p5.h, p6.h, p7.h}, l1 = {p4.l, p5.l, p6.l, p7.l};
        *(uint4v*)&Ah[srow][scg] = h0;  *(uint4v*)&Ah[srow][scg + 8] = h1;
        *(uint4v*)&Al[srow][scg] = l0;  *(uint4v*)&Al[srow][scg + 8] = l1;
      }
      {
        HL p0 = split2(bv0.x, bv0.y), p1 = split2(bv0.z, bv0.w);
        HL p2 = split2(bv1.x, bv1.y), p3 = split2(bv1.z, bv1.w);
        HL p4 = split2(bv2.x, bv2.y), p5 = split2(bv2.z, bv2.w);
        HL p6 = split2(bv3.x, bv3.y), p7 = split2(bv3.z, bv3.w);
        uint4v h0 = {p0.h, p1.h, p2.h, p3.h}, l0 = {p0.l, p1.l, p2.l, p3.l};
        uint4v h1 = {p4.h, p5.h, p6.h, p7.h}, l1 = {p4.l, p5.l, p6.l, p7.l};
        *(uint4v*)&Bh[srow][scg] = h0;  *(uint4v*)&Bh[srow][scg + 8] = h1;
        *(uint4v*)&Bl[srow][scg] = l0;  *(uint4v*)&Bl[srow][scg + 8] = l1;
      }
      __syncthreads();

      short8 ah[4], al[4], bh[4], bl[4];
#pragma unroll
      for (int m = 0; m < 4; ++m) {
        int r = wr * 64 + m * 16 + lr16;
        ah[m] = *(const short8*)&Ah[r][kof];
        al[m] = *(const short8*)&Al[r][kof];
      }
#pragma unroll
      for (int n = 0; n < 4; ++n) {
        int c = wc * 64 + n * 16 + lr16;
        bh[n] = *(const short8*)&Bh[c][kof];
        bl[n] = *(const short8*)&Bl[c][kof];
      }
#pragma unroll
      for (int m = 0; m < 4; ++m)
#pragma unroll
        for (int n = 0; n < 4; ++n) {
          acc[m][n] = __builtin_amdgcn_mfma_f32_16x16x32_bf16(ah[m], bh[n], acc[m][n], 0, 0, 0);
          acc[m][n] = __builtin_amdgcn_mfma_f32_16x16x32_bf16(ah[m], bl[n], acc[m][n], 0, 0, 0);
          acc[m][n] = __builtin_amdgcn_mfma_f32_16x16x32_bf16(al[m], bh[n], acc[m][n], 0, 0, 0);
        }
    }

#pragma unroll
    for (int m = 0; m < 4; ++m) {
#pragma unroll
      for (int n = 0; n < 4; ++n) {
        int gi0 = row0 + wr * 64 + m * 16 + rg;
        int gj = col0 + wc * 64 + n * 16 + cl;
#pragma unroll
        for (int r = 0; r < 4; ++r) {
          int gi = gi0 + r;
          Mout[(size_t)gi * D + gj] -= acc[m][n][r];
        }
      }
    }
  }
}

__global__ __launch_bounds__(256) void chol_fused_kernel(float* __restrict__ M,
                                                         unsigned* __restrict__ barbuf)
{
  __shared__ __align__(16) unsigned char smem[66560];
  float (*Ls)[NB + 1] = (float(*)[NB + 1])smem;
  float* dinv = (float*)(smem + NB * (NB + 1) * 4);   // 66048..66560
  unsigned* bar = barbuf;        // offset 0
  unsigned* rel = barbuf + 32;   // offset 128 B (separate cacheline)
  unsigned mygen = 0;

  for (int k = 0; k < D / NB; ++k) {
    int kb = k * NB;
    if (blockIdx.x == 0) potrf_device(M, kb, Ls);
    grid_barrier(bar, rel, &mygen);
    int T = D - kb - NB;
    if (T > 0) {
      trsm_device(M, kb, T, Ls, dinv);
      grid_barrier(bar, rel, &mygen);
      syrk1_device(M, kb, T / TSY, smem);
      grid_barrier(bar, rel, &mygen);
    }
  }
}

__global__ __launch_bounds__(256) void zero_upper_kernel(float* __restrict__ M)
{
  size_t idx = (size_t)blockIdx.x * 256 + threadIdx.x;
  int i = (int)(idx >> 12);
  int j = (int)(idx & (D - 1));
  if (j > i) M[idx] = 0.0f;
}

extern "C" void kernel_launch(void* const* d_in, const int* in_sizes, int n_in,
                              void* d_out, int out_size, void* d_ws, size_t ws_size,
                              hipStream_t stream)
{
  (void)in_sizes; (void)n_in; (void)ws_size; (void)out_size;
  const float* A  = (const float*)d_in[0];
  const float* nv = (const float*)d_in[1];
  float* M = (float*)d_out;

  // reset grid-barrier counters (d_ws is poisoned once, not re-poisoned per replay)
  hipMemsetAsync(d_ws, 0, 256, stream);

  syrk0_kernel<<<NTILES * (NTILES + 1) / 2, 256, 0, stream>>>(A, nv, M);

  chol_fused_kernel<<<NBLK, 256, 0, stream>>>(M, (unsigned*)d_ws);

  zero_upper_kernel<<<(int)(((size_t)D * D) / 256), 256, 0, stream>>>(M);
}

// Round 6
// 4600.482 us; speedup vs baseline: 1.9818x; 1.9818x over previous
//
#include <hip/hip_runtime.h>
#include <math.h>

#define D 4096
#define NB 128
#define TSY 128
#define KC 32
#define NTILES (D / TSY)
#define LDP 40   // padded LDS row stride in bf16 elems (80 B)

typedef __attribute__((ext_vector_type(8))) short short8;
typedef __attribute__((ext_vector_type(4))) float f32x4;
typedef __attribute__((ext_vector_type(4))) unsigned int uint4v;
typedef unsigned short ush;

__device__ __forceinline__ float softplusf(float x) {
  return fmaxf(x, 0.0f) + log1pf(expf(-fabsf(x)));
}

struct HL { unsigned int h, l; };

// split two fp32 into packed bf16 hi (truncated) and bf16 lo (residual)
__device__ __forceinline__ HL split2(float x0, float x1) {
  unsigned int b0 = __float_as_uint(x0), b1 = __float_as_uint(x1);
  unsigned int h0 = b0 & 0xFFFF0000u, h1 = b1 & 0xFFFF0000u;
  float r0 = x0 - __uint_as_float(h0);
  float r1 = x1 - __uint_as_float(h1);
  HL out;
  out.h = h1 | (h0 >> 16);
  out.l = (__float_as_uint(r1) & 0xFFFF0000u) | (__float_as_uint(r0) >> 16);
  return out;
}

// In-LDS Cholesky factor of a full 128x128 tile already resident in Ls.
// Wave 0 factors 16-col panels register-resident (shfl broadcasts, no LDS RMW
// chain); all 4 waves do the rank-16 trailing updates. Ends with __syncthreads.
__device__ void potrf_factor(float (*Ls)[NB + 1]) {
  int tid = threadIdx.x;
  int lane = tid & 63, wid = tid >> 6;
  int tx = tid & 15, ty = tid >> 4;

  for (int pp = 0; pp < 8; ++pp) {
    int pc0 = pp * 16;
    if (wid == 0) {
      int ra = lane, rb = lane + 64;
      bool va = (ra >= pc0), vb = (rb >= pc0);
      float xa[16], xb[16];
#pragma unroll
      for (int c = 0; c < 16; ++c) {
        xa[c] = va ? Ls[ra][pc0 + c] : 0.0f;
        xb[c] = vb ? Ls[rb][pc0 + c] : 0.0f;
      }
#pragma unroll
      for (int j = 0; j < 16; ++j) {
        int jj = pc0 + j;
        float dv = (jj < 64) ? __shfl(xa[j], jj) : __shfl(xb[j], jj - 64);
        float s = 1.0f / sqrtf(dv);
        xa[j] *= s;
        xb[j] *= s;
        float mja = (ra > jj) ? xa[j] : 0.0f;
        float mjb = (rb > jj) ? xb[j] : 0.0f;
#pragma unroll
        for (int c = j + 1; c < 16; ++c) {
          int rc = pc0 + c;
          float lc = (rc < 64) ? __shfl(xa[j], rc) : __shfl(xb[j], rc - 64);
          xa[c] -= mja * lc;
          xb[c] -= mjb * lc;
        }
      }
      if (va) {
#pragma unroll
        for (int c = 0; c < 16; ++c) Ls[ra][pc0 + c] = xa[c];
      }
      if (vb) {
#pragma unroll
        for (int c = 0; c < 16; ++c) Ls[rb][pc0 + c] = xb[c];
      }
    }
    __syncthreads();

    int s0 = pc0 + 16;
    if (s0 < NB) {
      int r0 = ty * 8, c0 = tx * 8;
      if (r0 >= s0 && c0 >= s0) {
        float acc[8][8];
#pragma unroll
        for (int rr = 0; rr < 8; ++rr) {
          float4 m0 = *(const float4*)&Ls[r0 + rr][c0];
          float4 m1 = *(const float4*)&Ls[r0 + rr][c0 + 4];
          acc[rr][0] = m0.x; acc[rr][1] = m0.y; acc[rr][2] = m0.z; acc[rr][3] = m0.w;
          acc[rr][4] = m1.x; acc[rr][5] = m1.y; acc[rr][6] = m1.z; acc[rr][7] = m1.w;
        }
#pragma unroll
        for (int q = 0; q < 16; ++q) {
          float av[8], bv[8];
#pragma unroll
          for (int rr = 0; rr < 8; ++rr) av[rr] = Ls[r0 + rr][pc0 + q];
#pragma unroll
          for (int cc = 0; cc < 8; ++cc) bv[cc] = Ls[c0 + cc][pc0 + q];
#pragma unroll
          for (int rr = 0; rr < 8; ++rr)
#pragma unroll
            for (int cc = 0; cc < 8; ++cc) acc[rr][cc] -= av[rr] * bv[cc];
        }
#pragma unroll
        for (int rr = 0; rr < 8; ++rr) {
          *(float4*)&Ls[r0 + rr][c0] =
              make_float4(acc[rr][0], acc[rr][1], acc[rr][2], acc[rr][3]);
          *(float4*)&Ls[r0 + rr][c0 + 4] =
              make_float4(acc[rr][4], acc[rr][5], acc[rr][6], acc[rr][7]);
        }
      }
    }
    __syncthreads();
  }
}

// store factored tile: L in lower, zeros in strict upper (full coalesced rows)
__device__ void potrf_store(float* Msrc, float (*Ls)[NB + 1]) {
  int tid = threadIdx.x;
  for (int idx = tid; idx < NB * NB; idx += 256) {
    int i = idx >> 7, j = idx & (NB - 1);
    Msrc[(size_t)i * D + j] = (j <= i) ? Ls[i][j] : 0.0f;
  }
}

// ---------------- syrk0: M = A·A^T + diag(softplus(n)), lower tiles ----------------
// Fused: block 0 additionally potrfs diag tile 0; strict-lower blocks zero
// their mirror (upper) tile.
__global__ __launch_bounds__(256) void syrk0_kernel(
    const float* __restrict__ Asrc, const float* __restrict__ nvec,
    float* __restrict__ Mout)
{
  __shared__ __align__(16) unsigned char smem[66560];
  ush (*Ah)[LDP] = (ush(*)[LDP])(smem);
  ush (*Al)[LDP] = (ush(*)[LDP])(smem + 10240);
  ush (*Bh)[LDP] = (ush(*)[LDP])(smem + 20480);
  ush (*Bl)[LDP] = (ush(*)[LDP])(smem + 30720);
  float (*Ls)[NB + 1] = (float(*)[NB + 1])smem;

  int b = blockIdx.x;
  int ti = (int)((sqrtf(8.0f * (float)b + 1.0f) - 1.0f) * 0.5f);
  while ((ti + 1) * (ti + 2) / 2 <= b) ++ti;
  while (ti * (ti + 1) / 2 > b) --ti;
  int tj = b - ti * (ti + 1) / 2;
  int row0 = ti * TSY, col0 = tj * TSY;

  int tid = threadIdx.x;
  int lane = tid & 63, wid = tid >> 6;
  int wr = wid >> 1, wc = wid & 1;
  int srow = tid >> 1;
  int scg = (tid & 1) * 16;

  f32x4 acc[4][4];
#pragma unroll
  for (int m = 0; m < 4; ++m)
#pragma unroll
    for (int n = 0; n < 4; ++n) acc[m][n] = (f32x4){0.f, 0.f, 0.f, 0.f};

  int lr16 = lane & 15, kof = (lane >> 4) * 8;

  for (int kk = 0; kk < D; kk += KC) {
    const float* pa = Asrc + (size_t)(row0 + srow) * D + kk + scg;
    const float* pb = Asrc + (size_t)(col0 + srow) * D + kk + scg;
    float4 av0 = *(const float4*)(pa + 0), av1 = *(const float4*)(pa + 4);
    float4 av2 = *(const float4*)(pa + 8), av3 = *(const float4*)(pa + 12);
    float4 bv0 = *(const float4*)(pb + 0), bv1 = *(const float4*)(pb + 4);
    float4 bv2 = *(const float4*)(pb + 8), bv3 = *(const float4*)(pb + 12);

    __syncthreads();
    {
      HL p0 = split2(av0.x, av0.y), p1 = split2(av0.z, av0.w);
      HL p2 = split2(av1.x, av1.y), p3 = split2(av1.z, av1.w);
      HL p4 = split2(av2.x, av2.y), p5 = split2(av2.z, av2.w);
      HL p6 = split2(av3.x, av3.y), p7 = split2(av3.z, av3.w);
      uint4v h0 = {p0.h, p1.h, p2.h, p3.h}, l0 = {p0.l, p1.l, p2.l, p3.l};
      uint4v h1 = {p4.h, p5.h, p6.h, p7.h}, l1 = {p4.l, p5.l, p6.l, p7.l};
      *(uint4v*)&Ah[srow][scg] = h0;  *(uint4v*)&Ah[srow][scg + 8] = h1;
      *(uint4v*)&Al[srow][scg] = l0;  *(uint4v*)&Al[srow][scg + 8] = l1;
    }
    {
      HL p0 = split2(bv0.x, bv0.y), p1 = split2(bv0.z, bv0.w);
      HL p2 = split2(bv1.x, bv1.y), p3 = split2(bv1.z, bv1.w);
      HL p4 = split2(bv2.x, bv2.y), p5 = split2(bv2.z, bv2.w);
      HL p6 = split2(bv3.x, bv3.y), p7 = split2(bv3.z, bv3.w);
      uint4v h0 = {p0.h, p1.h, p2.h, p3.h}, l0 = {p0.l, p1.l, p2.l, p3.l};
      uint4v h1 = {p4.h, p5.h, p6.h, p7.h}, l1 = {p4.l, p5.l, p6.l, p7.l};
      *(uint4v*)&Bh[srow][scg] = h0;  *(uint4v*)&Bh[srow][scg + 8] = h1;
      *(uint4v*)&Bl[srow][scg] = l0;  *(uint4v*)&Bl[srow][scg + 8] = l1;
    }
    __syncthreads();

    short8 ah[4], al[4], bh[4], bl[4];
#pragma unroll
    for (int m = 0; m < 4; ++m) {
      int r = wr * 64 + m * 16 + lr16;
      ah[m] = *(const short8*)&Ah[r][kof];
      al[m] = *(const short8*)&Al[r][kof];
    }
#pragma unroll
    for (int n = 0; n < 4; ++n) {
      int c = wc * 64 + n * 16 + lr16;
      bh[n] = *(const short8*)&Bh[c][kof];
      bl[n] = *(const short8*)&Bl[c][kof];
    }
#pragma unroll
    for (int m = 0; m < 4; ++m)
#pragma unroll
      for (int n = 0; n < 4; ++n) {
        acc[m][n] = __builtin_amdgcn_mfma_f32_16x16x32_bf16(ah[m], bh[n], acc[m][n], 0, 0, 0);
        acc[m][n] = __builtin_amdgcn_mfma_f32_16x16x32_bf16(ah[m], bl[n], acc[m][n], 0, 0, 0);
        acc[m][n] = __builtin_amdgcn_mfma_f32_16x16x32_bf16(al[m], bh[n], acc[m][n], 0, 0, 0);
      }
  }

  int cl = lane & 15, rg = (lane >> 4) * 4;

  if (b == 0) {
    // fused potrf of diag tile 0: stage acc(+softplus) into Ls, factor, store
    __syncthreads();   // staging reads done before smem reuse as Ls
#pragma unroll
    for (int m = 0; m < 4; ++m)
#pragma unroll
      for (int n = 0; n < 4; ++n) {
        int li0 = wr * 64 + m * 16 + rg;
        int lj = wc * 64 + n * 16 + cl;
#pragma unroll
        for (int r = 0; r < 4; ++r) {
          int li = li0 + r;
          float v = acc[m][n][r];
          if (li == lj) v += softplusf(nvec[li]);
          Ls[li][lj] = v;
        }
      }
    __syncthreads();
    potrf_factor(Ls);
    potrf_store(Mout, Ls);
    return;
  }

#pragma unroll
  for (int m = 0; m < 4; ++m) {
#pragma unroll
    for (int n = 0; n < 4; ++n) {
      int gi0 = row0 + wr * 64 + m * 16 + rg;
      int gj = col0 + wc * 64 + n * 16 + cl;
#pragma unroll
      for (int r = 0; r < 4; ++r) {
        int gi = gi0 + r;
        float v = acc[m][n][r];
        if (gi == gj) v += softplusf(nvec[gi]);
        Mout[(size_t)gi * D + gj] = v;
      }
    }
  }

  // strict-lower blocks zero their mirror (upper) tile: rows col0.., cols row0..
  if (ti > tj) {
    float4 z = make_float4(0.f, 0.f, 0.f, 0.f);
    int zr = tid >> 1;
    int zc0 = (tid & 1) * 64;
    float* zp = Mout + (size_t)(col0 + zr) * D + row0 + zc0;
#pragma unroll
    for (int q = 0; q < 16; ++q) *(float4*)(zp + 4 * q) = z;
  }
}

// ---------------- trailing update: M22 -= X·X^T (tiles of t x t lower grid) ----------
// Fused: block 0 (next diag tile) factors its updated tile in LDS and stores
// L + zeroed upper instead of writing the raw update.
__global__ __launch_bounds__(256) void syrk1_kernel(float* __restrict__ M, int kb)
{
  __shared__ __align__(16) unsigned char smem[66560];
  ush (*Ah)[LDP] = (ush(*)[LDP])(smem);
  ush (*Al)[LDP] = (ush(*)[LDP])(smem + 10240);
  ush (*Bh)[LDP] = (ush(*)[LDP])(smem + 20480);
  ush (*Bl)[LDP] = (ush(*)[LDP])(smem + 30720);
  float (*Ls)[NB + 1] = (float(*)[NB + 1])smem;

  const float* Asrc = M + (size_t)(kb + NB) * D + kb;      // panel X
  float* Mout = M + (size_t)(kb + NB) * D + (kb + NB);     // trailing matrix

  int s = blockIdx.x;
  int ti = (int)((sqrtf(8.0f * (float)s + 1.0f) - 1.0f) * 0.5f);
  while ((ti + 1) * (ti + 2) / 2 <= s) ++ti;
  while (ti * (ti + 1) / 2 > s) --ti;
  int tj = s - ti * (ti + 1) / 2;
  int row0 = ti * TSY, col0 = tj * TSY;

  int tid = threadIdx.x;
  int lane = tid & 63, wid = tid >> 6;
  int wr = wid >> 1, wc = wid & 1;
  int srow = tid >> 1;
  int scg = (tid & 1) * 16;
  int lr16 = lane & 15, kof = (lane >> 4) * 8;
  int cl = lane & 15, rg = (lane >> 4) * 4;

  f32x4 acc[4][4];
#pragma unroll
  for (int m = 0; m < 4; ++m)
#pragma unroll
    for (int n = 0; n < 4; ++n) acc[m][n] = (f32x4){0.f, 0.f, 0.f, 0.f};

  for (int kk = 0; kk < NB; kk += KC) {
    const float* pa = Asrc + (size_t)(row0 + srow) * D + kk + scg;
    const float* pb = Asrc + (size_t)(col0 + srow) * D + kk + scg;
    float4 av0 = *(const float4*)(pa + 0), av1 = *(const float4*)(pa + 4);
    float4 av2 = *(const float4*)(pa + 8), av3 = *(const float4*)(pa + 12);
    float4 bv0 = *(const float4*)(pb + 0), bv1 = *(const float4*)(pb + 4);
    float4 bv2 = *(const float4*)(pb + 8), bv3 = *(const float4*)(pb + 12);

    __syncthreads();
    {
      HL p0 = split2(av0.x, av0.y), p1 = split2(av0.z, av0.w);
      HL p2 = split2(av1.x, av1.y), p3 = split2(av1.z, av1.w);
      HL p4 = split2(av2.x, av2.y), p5 = split2(av2.z, av2.w);
      HL p6 = split2(av3.x, av3.y), p7 = split2(av3.z, av3.w);
      uint4v h0 = {p0.h, p1.h, p2.h, p3.h}, l0 = {p0.l, p1.l, p2.l, p3.l};
      uint4v h1 = {p4.h, p5.h, p6.h, p7.h}, l1 = {p4.l, p5.l, p6.l, p7.l};
      *(uint4v*)&Ah[srow][scg] = h0;  *(uint4v*)&Ah[srow][scg + 8] = h1;
      *(uint4v*)&Al[srow][scg] = l0;  *(uint4v*)&Al[srow][scg + 8] = l1;
    }
    {
      HL p0 = split2(bv0.x, bv0.y), p1 = split2(bv0.z, bv0.w);
      HL p2 = split2(bv1.x, bv1.y), p3 = split2(bv1.z, bv1.w);
      HL p4 = split2(bv2.x, bv2.y), p5 = split2(bv2.z, bv2.w);
      HL p6 = split2(bv3.x, bv3.y), p7 = split2(bv3.z, bv3.w);
      uint4v h0 = {p0.h, p1.h, p2.h, p3.h}, l0 = {p0.l, p1.l, p2.l, p3.l};
      uint4v h1 = {p4.h, p5.h, p6.h, p7.h}, l1 = {p4.l, p5.l, p6.l, p7.l};
      *(uint4v*)&Bh[srow][scg] = h0;  *(uint4v*)&Bh[srow][scg + 8] = h1;
      *(uint4v*)&Bl[srow][scg] = l0;  *(uint4v*)&Bl[srow][scg + 8] = l1;
    }
    __syncthreads();

    short8 ah[4], al[4], bh[4], bl[4];
#pragma unroll
    for (int m = 0; m < 4; ++m) {
      int r = wr * 64 + m * 16 + lr16;
      ah[m] = *(const short8*)&Ah[r][kof];
      al[m] = *(const short8*)&Al[r][kof];
    }
#pragma unroll
    for (int n = 0; n < 4; ++n) {
      int c = wc * 64 + n * 16 + lr16;
      bh[n] = *(const short8*)&Bh[c][kof];
      bl[n] = *(const short8*)&Bl[c][kof];
    }
#pragma unroll
    for (int m = 0; m < 4; ++m)
#pragma unroll
      for (int n = 0; n < 4; ++n) {
        acc[m][n] = __builtin_amdgcn_mfma_f32_16x16x32_bf16(ah[m], bh[n], acc[m][n], 0, 0, 0);
        acc[m][n] = __builtin_amdgcn_mfma_f32_16x16x32_bf16(ah[m], bl[n], acc[m][n], 0, 0, 0);
        acc[m][n] = __builtin_amdgcn_mfma_f32_16x16x32_bf16(al[m], bh[n], acc[m][n], 0, 0, 0);
      }
  }

  if (s == 0) {
    // fused potrf of next diag tile: updated = oldM - acc staged into Ls
    __syncthreads();   // staging reads done before smem reuse as Ls
#pragma unroll
    for (int m = 0; m < 4; ++m)
#pragma unroll
      for (int n = 0; n < 4; ++n) {
        int li0 = wr * 64 + m * 16 + rg;
        int lj = wc * 64 + n * 16 + cl;
#pragma unroll
        for (int r = 0; r < 4; ++r) {
          int li = li0 + r;
          Ls[li][lj] = Mout[(size_t)li * D + lj] - acc[m][n][r];
        }
      }
    __syncthreads();
    potrf_factor(Ls);
    potrf_store(Mout, Ls);
    return;
  }

#pragma unroll
  for (int m = 0; m < 4; ++m) {
#pragma unroll
    for (int n = 0; n < 4; ++n) {
      int gi0 = row0 + wr * 64 + m * 16 + rg;
      int gj = col0 + wc * 64 + n * 16 + cl;
#pragma unroll
      for (int r = 0; r < 4; ++r) {
        int gi = gi0 + r;
        Mout[(size_t)gi * D + gj] -= acc[m][n][r];
      }
    }
  }
}

// Panel solve: rows [kb+NB, D) of cols [kb, kb+NB): X * L11^T = M21.
__global__ __launch_bounds__(256) void trsm_kernel(float* __restrict__ M, int kb)
{
  __shared__ float Ls[NB][NB + 1];
  __shared__ float dinv[NB];
  int tid = threadIdx.x;
  const float* Lsrc = M + (size_t)kb * D + kb;
  for (int idx = tid; idx < NB * NB; idx += 256) {
    int i = idx >> 7, j = idx & (NB - 1);
    Ls[i][j] = (j <= i) ? Lsrc[(size_t)i * D + j] : 0.0f;
  }
  __syncthreads();
  if (tid < NB) dinv[tid] = 1.0f / Ls[tid][tid];
  __syncthreads();
  int lane = tid & 63, w = tid >> 6;
  size_t r0 = (size_t)(kb + NB) + (size_t)blockIdx.x * 8 + w * 2;
  float* p0 = M + r0 * D + kb;
  float* p1 = p0 + D;
  float x0l = p0[lane], x0h = p0[64 + lane];
  float x1l = p1[lane], x1h = p1[64 + lane];
  for (int p = 0; p < 64; ++p) {
    float dv = dinv[p];
    float xp0 = __shfl(x0l, p) * dv;
    float xp1 = __shfl(x1l, p) * dv;
    float Llo = Ls[lane][p];
    float Lhi = Ls[64 + lane][p];
    if (lane == p)      { x0l = xp0; x1l = xp1; }
    else if (lane > p)  { x0l -= xp0 * Llo; x1l -= xp1 * Llo; }
    x0h -= xp0 * Lhi;
    x1h -= xp1 * Lhi;
  }
  for (int p = 64; p < NB; ++p) {
    int q = p - 64;
    float dv = dinv[p];
    float xp0 = __shfl(x0h, q) * dv;
    float xp1 = __shfl(x1h, q) * dv;
    float Lhi = Ls[64 + lane][p];
    if (lane == q)      { x0h = xp0; x1h = xp1; }
    else if (lane > q)  { x0h -= xp0 * Lhi; x1h -= xp1 * Lhi; }
  }
  p0[lane] = x0l; p0[64 + lane] = x0h;
  p1[lane] = x1l; p1[64 + lane] = x1h;
}

extern "C" void kernel_launch(void* const* d_in, const int* in_sizes, int n_in,
                              void* d_out, int out_size, void* d_ws, size_t ws_size,
                              hipStream_t stream)
{
  (void)in_sizes; (void)n_in; (void)d_ws; (void)ws_size; (void)out_size;
  const float* A  = (const float*)d_in[0];
  const float* nv = (const float*)d_in[1];
  float* M = (float*)d_out;

  // M = A·A^T + softplus diag (lower+diag tiles), mirror-zero upper tiles,
  // fused potrf of diag tile 0
  syrk0_kernel<<<NTILES * (NTILES + 1) / 2, 256, 0, stream>>>(A, nv, M);

  for (int k = 0; k <= 30; ++k) {
    int kb = k * NB;
    int T = D - kb - NB;
    int t = T / TSY;
    trsm_kernel<<<T / 8, 256, 0, stream>>>(M, kb);
    // trailing update + fused potrf of diag tile k+1
    syrk1_kernel<<<t * (t + 1) / 2, 256, 0, stream>>>(M, kb);
  }
}

// Round 7
// 4341.967 us; speedup vs baseline: 2.0998x; 1.0595x over previous
//
#include <hip/hip_runtime.h>
#include <math.h>

#define D 4096
#define NB 128
#define TSY 128
#define KC 32
#define NTILES (D / TSY)
#define LDP 40   // padded LDS row stride in bf16 elems (80 B)

typedef __attribute__((ext_vector_type(8))) short short8;
typedef __attribute__((ext_vector_type(4))) float f32x4;
typedef __attribute__((ext_vector_type(4))) unsigned int uint4v;
typedef unsigned short ush;

__device__ __forceinline__ float softplusf(float x) {
  return fmaxf(x, 0.0f) + log1pf(expf(-fabsf(x)));
}

struct HL { unsigned int h, l; };

// split two fp32 into packed bf16 hi (truncated) and bf16 lo (residual)
__device__ __forceinline__ HL split2(float x0, float x1) {
  unsigned int b0 = __float_as_uint(x0), b1 = __float_as_uint(x1);
  unsigned int h0 = b0 & 0xFFFF0000u, h1 = b1 & 0xFFFF0000u;
  float r0 = x0 - __uint_as_float(h0);
  float r1 = x1 - __uint_as_float(h1);
  HL out;
  out.h = h1 | (h0 >> 16);
  out.l = (__float_as_uint(r1) & 0xFFFF0000u) | (__float_as_uint(r0) >> 16);
  return out;
}

// In-LDS Cholesky factor of a 128x128 tile resident in Ls (upper may hold
// symmetric garbage; never read). Panel factor uses UNNORMALIZED columns
// (Schur update v_c -= v_j * v_j[rc] / d_j via v_rcp) so the per-column
// dependent chain is shfl->fma only; columns are normalized once per panel.
__device__ void potrf_factor(float (*Ls)[NB + 1]) {
  int tid = threadIdx.x;
  int lane = tid & 63, wid = tid >> 6;
  int tx = tid & 15, ty = tid >> 4;

  for (int pp = 0; pp < 8; ++pp) {
    int pc0 = pp * 16;
    if (wid == 0) {
      int ra = lane, rb = lane + 64;
      bool va = (ra >= pc0), vb = (rb >= pc0);
      float xa[16], xb[16];
#pragma unroll
      for (int c = 0; c < 16; ++c) {
        xa[c] = va ? Ls[ra][pc0 + c] : 0.0f;
        xb[c] = vb ? Ls[rb][pc0 + c] : 0.0f;
      }
#pragma unroll
      for (int j = 0; j < 16; ++j) {
        int jj = pc0 + j;
        float dv = (jj < 64) ? __shfl(xa[j], jj) : __shfl(xb[j], jj - 64);
        float di = __builtin_amdgcn_rcpf(dv);
        float ta = (ra > jj) ? xa[j] * di : 0.0f;
        float tb = (rb > jj) ? xb[j] * di : 0.0f;
#pragma unroll
        for (int c = j + 1; c < 16; ++c) {
          int rc = pc0 + c;
          float lc = (rc < 64) ? __shfl(xa[j], rc) : __shfl(xb[j], rc - 64);
          xa[c] -= ta * lc;
          xb[c] -= tb * lc;
        }
      }
      // normalize the 16 columns: L[:,c] = v_c / sqrt(d_c)
#pragma unroll
      for (int c = 0; c < 16; ++c) {
        int rc = pc0 + c;
        float dc = (rc < 64) ? __shfl(xa[c], rc) : __shfl(xb[c], rc - 64);
        float sc = __builtin_amdgcn_rsqf(dc);
        xa[c] *= sc;
        xb[c] *= sc;
      }
      if (va) {
#pragma unroll
        for (int c = 0; c < 16; ++c) Ls[ra][pc0 + c] = xa[c];
      }
      if (vb) {
#pragma unroll
        for (int c = 0; c < 16; ++c) Ls[rb][pc0 + c] = xb[c];
      }
    }
    __syncthreads();

    int s0 = pc0 + 16;
    if (s0 < NB) {
      int r0 = ty * 8, c0 = tx * 8;
      if (r0 >= s0 && c0 >= s0) {
        float acc[8][8];
#pragma unroll
        for (int rr = 0; rr < 8; ++rr) {
          float4 m0 = *(const float4*)&Ls[r0 + rr][c0];
          float4 m1 = *(const float4*)&Ls[r0 + rr][c0 + 4];
          acc[rr][0] = m0.x; acc[rr][1] = m0.y; acc[rr][2] = m0.z; acc[rr][3] = m0.w;
          acc[rr][4] = m1.x; acc[rr][5] = m1.y; acc[rr][6] = m1.z; acc[rr][7] = m1.w;
        }
#pragma unroll
        for (int q = 0; q < 16; ++q) {
          float av[8], bv[8];
#pragma unroll
          for (int rr = 0; rr < 8; ++rr) av[rr] = Ls[r0 + rr][pc0 + q];
#pragma unroll
          for (int cc = 0; cc < 8; ++cc) bv[cc] = Ls[c0 + cc][pc0 + q];
#pragma unroll
          for (int rr = 0; rr < 8; ++rr)
#pragma unroll
            for (int cc = 0; cc < 8; ++cc) acc[rr][cc] -= av[rr] * bv[cc];
        }
#pragma unroll
        for (int rr = 0; rr < 8; ++rr) {
          *(float4*)&Ls[r0 + rr][c0] =
              make_float4(acc[rr][0], acc[rr][1], acc[rr][2], acc[rr][3]);
          *(float4*)&Ls[r0 + rr][c0 + 4] =
              make_float4(acc[rr][4], acc[rr][5], acc[rr][6], acc[rr][7]);
        }
      }
    }
    __syncthreads();
  }
}

// store factored tile: L in lower, zeros in strict upper (coalesced rows)
__device__ void potrf_store(float* Msrc, float (*Ls)[NB + 1]) {
  int tid = threadIdx.x;
  for (int idx = tid; idx < NB * NB; idx += 256) {
    int i = idx >> 7, j = idx & (NB - 1);
    Msrc[(size_t)i * D + j] = (j <= i) ? Ls[i][j] : 0.0f;
  }
}

// standalone potrf of diag tile at (kb,kb)
__global__ __launch_bounds__(256) void potrf_kernel(float* __restrict__ M, int kb)
{
  __shared__ float Ls[NB][NB + 1];
  int tid = threadIdx.x;
  float* Msrc = M + (size_t)kb * D + kb;
  for (int idx = tid; idx < NB * NB; idx += 256) {
    int i = idx >> 7, j = idx & (NB - 1);
    Ls[i][j] = Msrc[(size_t)i * D + j];
  }
  __syncthreads();
  potrf_factor(Ls);
  potrf_store(Msrc, Ls);
}

// ---------------- syrk0: M = A·A^T + diag(softplus(n)), lower tiles -----------
// strict-lower blocks also zero their mirror (upper) tile. 40KB LDS, 3 blk/CU.
__global__ __launch_bounds__(256) void syrk0_kernel(
    const float* __restrict__ Asrc, const float* __restrict__ nvec,
    float* __restrict__ Mout)
{
  __shared__ ush Ah[TSY][LDP], Al[TSY][LDP];
  __shared__ ush Bh[TSY][LDP], Bl[TSY][LDP];

  int b = blockIdx.x;
  int ti = (int)((sqrtf(8.0f * (float)b + 1.0f) - 1.0f) * 0.5f);
  while ((ti + 1) * (ti + 2) / 2 <= b) ++ti;
  while (ti * (ti + 1) / 2 > b) --ti;
  int tj = b - ti * (ti + 1) / 2;
  int row0 = ti * TSY, col0 = tj * TSY;

  int tid = threadIdx.x;
  int lane = tid & 63, wid = tid >> 6;
  int wr = wid >> 1, wc = wid & 1;
  int srow = tid >> 1;
  int scg = (tid & 1) * 16;

  f32x4 acc[4][4];
#pragma unroll
  for (int m = 0; m < 4; ++m)
#pragma unroll
    for (int n = 0; n < 4; ++n) acc[m][n] = (f32x4){0.f, 0.f, 0.f, 0.f};

  int lr16 = lane & 15, kof = (lane >> 4) * 8;

  for (int kk = 0; kk < D; kk += KC) {
    const float* pa = Asrc + (size_t)(row0 + srow) * D + kk + scg;
    const float* pb = Asrc + (size_t)(col0 + srow) * D + kk + scg;
    float4 av0 = *(const float4*)(pa + 0), av1 = *(const float4*)(pa + 4);
    float4 av2 = *(const float4*)(pa + 8), av3 = *(const float4*)(pa + 12);
    float4 bv0 = *(const float4*)(pb + 0), bv1 = *(const float4*)(pb + 4);
    float4 bv2 = *(const float4*)(pb + 8), bv3 = *(const float4*)(pb + 12);

    __syncthreads();
    {
      HL p0 = split2(av0.x, av0.y), p1 = split2(av0.z, av0.w);
      HL p2 = split2(av1.x, av1.y), p3 = split2(av1.z, av1.w);
      HL p4 = split2(av2.x, av2.y), p5 = split2(av2.z, av2.w);
      HL p6 = split2(av3.x, av3.y), p7 = split2(av3.z, av3.w);
      uint4v h0 = {p0.h, p1.h, p2.h, p3.h}, l0 = {p0.l, p1.l, p2.l, p3.l};
      uint4v h1 = {p4.h, p5.h, p6.h, p7.h}, l1 = {p4.l, p5.l, p6.l, p7.l};
      *(uint4v*)&Ah[srow][scg] = h0;  *(uint4v*)&Ah[srow][scg + 8] = h1;
      *(uint4v*)&Al[srow][scg] = l0;  *(uint4v*)&Al[srow][scg + 8] = l1;
    }
    {
      HL p0 = split2(bv0.x, bv0.y), p1 = split2(bv0.z, bv0.w);
      HL p2 = split2(bv1.x, bv1.y), p3 = split2(bv1.z, bv1.w);
      HL p4 = split2(bv2.x, bv2.y), p5 = split2(bv2.z, bv2.w);
      HL p6 = split2(bv3.x, bv3.y), p7 = split2(bv3.z, bv3.w);
      uint4v h0 = {p0.h, p1.h, p2.h, p3.h}, l0 = {p0.l, p1.l, p2.l, p3.l};
      uint4v h1 = {p4.h, p5.h, p6.h, p7.h}, l1 = {p4.l, p5.l, p6.l, p7.l};
      *(uint4v*)&Bh[srow][scg] = h0;  *(uint4v*)&Bh[srow][scg + 8] = h1;
      *(uint4v*)&Bl[srow][scg] = l0;  *(uint4v*)&Bl[srow][scg + 8] = l1;
    }
    __syncthreads();

    short8 ah[4], al[4], bh[4], bl[4];
#pragma unroll
    for (int m = 0; m < 4; ++m) {
      int r = wr * 64 + m * 16 + lr16;
      ah[m] = *(const short8*)&Ah[r][kof];
      al[m] = *(const short8*)&Al[r][kof];
    }
#pragma unroll
    for (int n = 0; n < 4; ++n) {
      int c = wc * 64 + n * 16 + lr16;
      bh[n] = *(const short8*)&Bh[c][kof];
      bl[n] = *(const short8*)&Bl[c][kof];
    }
#pragma unroll
    for (int m = 0; m < 4; ++m)
#pragma unroll
      for (int n = 0; n < 4; ++n) {
        acc[m][n] = __builtin_amdgcn_mfma_f32_16x16x32_bf16(ah[m], bh[n], acc[m][n], 0, 0, 0);
        acc[m][n] = __builtin_amdgcn_mfma_f32_16x16x32_bf16(ah[m], bl[n], acc[m][n], 0, 0, 0);
        acc[m][n] = __builtin_amdgcn_mfma_f32_16x16x32_bf16(al[m], bh[n], acc[m][n], 0, 0, 0);
      }
  }

  int cl = lane & 15, rg = (lane >> 4) * 4;
#pragma unroll
  for (int m = 0; m < 4; ++m) {
#pragma unroll
    for (int n = 0; n < 4; ++n) {
      int gi0 = row0 + wr * 64 + m * 16 + rg;
      int gj = col0 + wc * 64 + n * 16 + cl;
#pragma unroll
      for (int r = 0; r < 4; ++r) {
        int gi = gi0 + r;
        float v = acc[m][n][r];
        if (gi == gj) v += softplusf(nvec[gi]);
        Mout[(size_t)gi * D + gj] = v;
      }
    }
  }

  // strict-lower blocks zero their mirror (upper) tile
  if (ti > tj) {
    float4 z = make_float4(0.f, 0.f, 0.f, 0.f);
    int zr = tid >> 1;
    int zc0 = (tid & 1) * 64;
    float* zp = Mout + (size_t)(col0 + zr) * D + row0 + zc0;
#pragma unroll
    for (int q = 0; q < 16; ++q) *(float4*)(zp + 4 * q) = z;
  }
}

// ---------------- trailing update: M22 -= X·X^T; block 0 potrfs next diag ----
__global__ __launch_bounds__(256) void syrk1_kernel(float* __restrict__ M, int kb)
{
  __shared__ __align__(16) unsigned char smem[66560];
  ush (*Ah)[LDP] = (ush(*)[LDP])(smem);
  ush (*Al)[LDP] = (ush(*)[LDP])(smem + 10240);
  ush (*Bh)[LDP] = (ush(*)[LDP])(smem + 20480);
  ush (*Bl)[LDP] = (ush(*)[LDP])(smem + 30720);
  float (*Ls)[NB + 1] = (float(*)[NB + 1])smem;

  const float* Asrc = M + (size_t)(kb + NB) * D + kb;      // panel X
  float* Mout = M + (size_t)(kb + NB) * D + (kb + NB);     // trailing matrix

  int s = blockIdx.x;
  int ti = (int)((sqrtf(8.0f * (float)s + 1.0f) - 1.0f) * 0.5f);
  while ((ti + 1) * (ti + 2) / 2 <= s) ++ti;
  while (ti * (ti + 1) / 2 > s) --ti;
  int tj = s - ti * (ti + 1) / 2;
  int row0 = ti * TSY, col0 = tj * TSY;

  int tid = threadIdx.x;
  int lane = tid & 63, wid = tid >> 6;
  int wr = wid >> 1, wc = wid & 1;
  int srow = tid >> 1;
  int scg = (tid & 1) * 16;
  int lr16 = lane & 15, kof = (lane >> 4) * 8;
  int cl = lane & 15, rg = (lane >> 4) * 4;

  f32x4 acc[4][4];
#pragma unroll
  for (int m = 0; m < 4; ++m)
#pragma unroll
    for (int n = 0; n < 4; ++n) acc[m][n] = (f32x4){0.f, 0.f, 0.f, 0.f};

  for (int kk = 0; kk < NB; kk += KC) {
    const float* pa = Asrc + (size_t)(row0 + srow) * D + kk + scg;
    const float* pb = Asrc + (size_t)(col0 + srow) * D + kk + scg;
    float4 av0 = *(const float4*)(pa + 0), av1 = *(const float4*)(pa + 4);
    float4 av2 = *(const float4*)(pa + 8), av3 = *(const float4*)(pa + 12);
    float4 bv0 = *(const float4*)(pb + 0), bv1 = *(const float4*)(pb + 4);
    float4 bv2 = *(const float4*)(pb + 8), bv3 = *(const float4*)(pb + 12);

    __syncthreads();
    {
      HL p0 = split2(av0.x, av0.y), p1 = split2(av0.z, av0.w);
      HL p2 = split2(av1.x, av1.y), p3 = split2(av1.z, av1.w);
      HL p4 = split2(av2.x, av2.y), p5 = split2(av2.z, av2.w);
      HL p6 = split2(av3.x, av3.y), p7 = split2(av3.z, av3.w);
      uint4v h0 = {p0.h, p1.h, p2.h, p3.h}, l0 = {p0.l, p1.l, p2.l, p3.l};
      uint4v h1 = {p4.h, p5.h, p6.h, p7.h}, l1 = {p4.l, p5.l, p6.l, p7.l};
      *(uint4v*)&Ah[srow][scg] = h0;  *(uint4v*)&Ah[srow][scg + 8] = h1;
      *(uint4v*)&Al[srow][scg] = l0;  *(uint4v*)&Al[srow][scg + 8] = l1;
    }
    {
      HL p0 = split2(bv0.x, bv0.y), p1 = split2(bv0.z, bv0.w);
      HL p2 = split2(bv1.x, bv1.y), p3 = split2(bv1.z, bv1.w);
      HL p4 = split2(bv2.x, bv2.y), p5 = split2(bv2.z, bv2.w);
      HL p6 = split2(bv3.x, bv3.y), p7 = split2(bv3.z, bv3.w);
      uint4v h0 = {p0.h, p1.h, p2.h, p3.h}, l0 = {p0.l, p1.l, p2.l, p3.l};
      uint4v h1 = {p4.h, p5.h, p6.h, p7.h}, l1 = {p4.l, p5.l, p6.l, p7.l};
      *(uint4v*)&Bh[srow][scg] = h0;  *(uint4v*)&Bh[srow][scg + 8] = h1;
      *(uint4v*)&Bl[srow][scg] = l0;  *(uint4v*)&Bl[srow][scg + 8] = l1;
    }
    __syncthreads();

    short8 ah[4], al[4], bh[4], bl[4];
#pragma unroll
    for (int m = 0; m < 4; ++m) {
      int r = wr * 64 + m * 16 + lr16;
      ah[m] = *(const short8*)&Ah[r][kof];
      al[m] = *(const short8*)&Al[r][kof];
    }
#pragma unroll
    for (int n = 0; n < 4; ++n) {
      int c = wc * 64 + n * 16 + lr16;
      bh[n] = *(const short8*)&Bh[c][kof];
      bl[n] = *(const short8*)&Bl[c][kof];
    }
#pragma unroll
    for (int m = 0; m < 4; ++m)
#pragma unroll
      for (int n = 0; n < 4; ++n) {
        acc[m][n] = __builtin_amdgcn_mfma_f32_16x16x32_bf16(ah[m], bh[n], acc[m][n], 0, 0, 0);
        acc[m][n] = __builtin_amdgcn_mfma_f32_16x16x32_bf16(ah[m], bl[n], acc[m][n], 0, 0, 0);
        acc[m][n] = __builtin_amdgcn_mfma_f32_16x16x32_bf16(al[m], bh[n], acc[m][n], 0, 0, 0);
      }
  }

  if (s == 0) {
    // fused potrf of next diag tile: updated = oldM - acc staged into Ls
    __syncthreads();   // staging reads done before smem reuse as Ls
#pragma unroll
    for (int m = 0; m < 4; ++m)
#pragma unroll
      for (int n = 0; n < 4; ++n) {
        int li0 = wr * 64 + m * 16 + rg;
        int lj = wc * 64 + n * 16 + cl;
#pragma unroll
        for (int r = 0; r < 4; ++r) {
          int li = li0 + r;
          Ls[li][lj] = Mout[(size_t)li * D + lj] - acc[m][n][r];
        }
      }
    __syncthreads();
    potrf_factor(Ls);
    potrf_store(Mout, Ls);
    return;
  }

#pragma unroll
  for (int m = 0; m < 4; ++m) {
#pragma unroll
    for (int n = 0; n < 4; ++n) {
      int gi0 = row0 + wr * 64 + m * 16 + rg;
      int gj = col0 + wc * 64 + n * 16 + cl;
#pragma unroll
      for (int r = 0; r < 4; ++r) {
        int gi = gi0 + r;
        Mout[(size_t)gi * D + gj] -= acc[m][n][r];
      }
    }
  }
}

// Panel solve: rows [kb+NB, D) of cols [kb, kb+NB): X * L11^T = M21.
__global__ __launch_bounds__(256) void trsm_kernel(float* __restrict__ M, int kb)
{
  __shared__ float Ls[NB][NB + 1];
  __shared__ float dinv[NB];
  int tid = threadIdx.x;
  const float* Lsrc = M + (size_t)kb * D + kb;
  for (int idx = tid; idx < NB * NB; idx += 256) {
    int i = idx >> 7, j = idx & (NB - 1);
    Ls[i][j] = (j <= i) ? Lsrc[(size_t)i * D + j] : 0.0f;
  }
  __syncthreads();
  if (tid < NB) dinv[tid] = 1.0f / Ls[tid][tid];
  __syncthreads();
  int lane = tid & 63, w = tid >> 6;
  size_t r0 = (size_t)(kb + NB) + (size_t)blockIdx.x * 8 + w * 2;
  float* p0 = M + r0 * D + kb;
  float* p1 = p0 + D;
  float x0l = p0[lane], x0h = p0[64 + lane];
  float x1l = p1[lane], x1h = p1[64 + lane];
  for (int p = 0; p < 64; ++p) {
    float dv = dinv[p];
    float xp0 = __shfl(x0l, p) * dv;
    float xp1 = __shfl(x1l, p) * dv;
    float Llo = Ls[lane][p];
    float Lhi = Ls[64 + lane][p];
    if (lane == p)      { x0l = xp0; x1l = xp1; }
    else if (lane > p)  { x0l -= xp0 * Llo; x1l -= xp1 * Llo; }
    x0h -= xp0 * Lhi;
    x1h -= xp1 * Lhi;
  }
  for (int p = 64; p < NB; ++p) {
    int q = p - 64;
    float dv = dinv[p];
    float xp0 = __shfl(x0h, q) * dv;
    float xp1 = __shfl(x1h, q) * dv;
    float Lhi = Ls[64 + lane][p];
    if (lane == q)      { x0h = xp0; x1h = xp1; }
    else if (lane > q)  { x0h -= xp0 * Lhi; x1h -= xp1 * Lhi; }
  }
  p0[lane] = x0l; p0[64 + lane] = x0h;
  p1[lane] = x1l; p1[64 + lane] = x1h;
}

extern "C" void kernel_launch(void* const* d_in, const int* in_sizes, int n_in,
                              void* d_out, int out_size, void* d_ws, size_t ws_size,
                              hipStream_t stream)
{
  (void)in_sizes; (void)n_in; (void)d_ws; (void)ws_size; (void)out_size;
  const float* A  = (const float*)d_in[0];
  const float* nv = (const float*)d_in[1];
  float* M = (float*)d_out;

  // M = A·A^T + softplus diag (lower+diag tiles), mirror-zero upper tiles
  syrk0_kernel<<<NTILES * (NTILES + 1) / 2, 256, 0, stream>>>(A, nv, M);
  // factor diag tile 0
  potrf_kernel<<<1, 256, 0, stream>>>(M, 0);

  for (int k = 0; k <= 30; ++k) {
    int kb = k * NB;
    int T = D - kb - NB;
    int t = T / TSY;
    trsm_kernel<<<T / 8, 256, 0, stream>>>(M, kb);
    // trailing update + fused potrf of diag tile k+1
    syrk1_kernel<<<t * (t + 1) / 2, 256, 0, stream>>>(M, kb);
  }
}